// Round 3
// baseline (1036.915 us; speedup 1.0000x reference)
//
#include <hip/hip_runtime.h>

#define CCH 16

// ======================= common =======================
__global__ void zero_u32(unsigned* __restrict__ p, int n) {
    int i = blockIdx.x * blockDim.x + threadIdx.x;
    if (i < n) p[i] = 0u;
}

__global__ void zero_f4(float4* __restrict__ p, int n4) {
    int i = blockIdx.x * blockDim.x + threadIdx.x;
    if (i < n4) p[i] = make_float4(0.f, 0.f, 0.f, 0.f);
}

// ======================= binned path =======================
// pass 1: histogram of segment ids
__global__ void hist_kernel(const int* __restrict__ seg,
                            unsigned* __restrict__ counts, int N, int M) {
    int i = blockIdx.x * blockDim.x + threadIdx.x;
    if (i < N) {
        unsigned s = (unsigned)seg[i];
        if (s < (unsigned)M) atomicAdd(&counts[s], 1u);
    }
}

// pass 2: exclusive scan (2-level). Per-block (1024) exclusive scan, block
// totals to bsums. Reads complete before first barrier, writes after last
// barrier -> safe for in-place use.
__global__ void scan1(const unsigned* __restrict__ in, unsigned* __restrict__ out,
                      unsigned* __restrict__ bsums, int M) {
    __shared__ unsigned ws[16];
    int i = blockIdx.x * 1024 + threadIdx.x;
    int lane = threadIdx.x & 63, wid = threadIdx.x >> 6;
    unsigned v = (i < M) ? in[i] : 0u;
    unsigned x = v;
#pragma unroll
    for (int d = 1; d < 64; d <<= 1) {
        unsigned y = __shfl_up(x, d, 64);
        if (lane >= d) x += y;
    }
    if (lane == 63) ws[wid] = x;
    __syncthreads();
    if (threadIdx.x < 16) {
        unsigned w = ws[threadIdx.x];
#pragma unroll
        for (int d = 1; d < 16; d <<= 1) {
            unsigned y = __shfl_up(w, d, 16);
            if ((threadIdx.x & 15) >= d) w += y;
        }
        ws[threadIdx.x] = w;
    }
    __syncthreads();
    unsigned wprefix = wid ? ws[wid - 1] : 0u;
    if (i < M) out[i] = wprefix + x - v;  // exclusive prefix within block
    if (threadIdx.x == 0 && bsums) bsums[blockIdx.x] = ws[15];  // block total
}

__global__ void scan_add(unsigned* __restrict__ out, const unsigned* __restrict__ bsums,
                         int M) {
    int i = blockIdx.x * 1024 + threadIdx.x;
    if (i < M) out[i] += bsums[blockIdx.x];
}

// pass 3: scatter point indices into slots; offsets: starts -> ends.
__global__ void scatter_slots(const int* __restrict__ seg,
                              unsigned* __restrict__ offsets,
                              unsigned* __restrict__ slots, int N, int M) {
    int i = blockIdx.x * blockDim.x + threadIdx.x;
    if (i < N) {
        unsigned s = (unsigned)seg[i];
        if (s < (unsigned)M) {
            unsigned pos = atomicAdd(&offsets[s], 1u);
            if (pos < (unsigned)N) slots[pos] = (unsigned)i;  // bounds-guarded
        }
    }
}

// pass 4: gather rows, reduce, divide. Lanes c=0..15 of a segment read 16
// consecutive floats of each point row -> one 64B request per point.
__global__ void gather_mean(const float* __restrict__ in,
                            const unsigned* __restrict__ slots,
                            const unsigned* __restrict__ ends,
                            const unsigned* __restrict__ counts,
                            float* __restrict__ out, int M, int N) {
    int t = blockIdx.x * blockDim.x + threadIdx.x;
    int s = t >> 4, c = t & 15;
    if (s >= M) return;
    unsigned n = counts[s];
    unsigned end = ends[s];
    if (end > (unsigned)N) end = (unsigned)N;
    unsigned start = (n <= end) ? end - n : 0u;
    float acc = 0.0f;
    for (unsigned i = start; i < end; ++i) {
        unsigned p = slots[i];
        acc += in[(size_t)p * CCH + c];
    }
    out[(size_t)s * CCH + c] = acc / (float)(n ? n : 1u);
}

// ======================= fallback (round-1 atomic) path =======================
__global__ void zero_f(float* __restrict__ p, int n) {
    int i = blockIdx.x * blockDim.x + threadIdx.x;
    if (i < n) p[i] = 0.0f;
}

__global__ void scatter_add_kernel(const float* __restrict__ in,
                                   const int* __restrict__ seg,
                                   float* __restrict__ sums,
                                   float* __restrict__ counts,
                                   int N) {
    int tid = blockIdx.x * blockDim.x + threadIdx.x;
    int p = tid >> 4;
    int c = tid & 15;
    if (p >= N) return;
    int s = seg[p];
    float v = in[tid];
    unsafeAtomicAdd(&sums[s * CCH + c], v);
    if (c == 0) unsafeAtomicAdd(&counts[s], 1.0f);
}

__global__ void finalize_kernel(float4* __restrict__ out,
                                const float* __restrict__ counts,
                                int n4) {
    int i = blockIdx.x * blockDim.x + threadIdx.x;
    if (i >= n4) return;
    int m = i >> 2;
    float inv = 1.0f / fmaxf(counts[m], 1.0f);
    float4 v = out[i];
    v.x *= inv; v.y *= inv; v.z *= inv; v.w *= inv;
    out[i] = v;
}

// ======================= launch =======================
extern "C" void kernel_launch(void* const* d_in, const int* in_sizes, int n_in,
                              void* d_out, int out_size, void* d_ws, size_t ws_size,
                              hipStream_t stream) {
    const float* in  = (const float*)d_in[0];
    const int*   seg = (const int*)d_in[1];
    float* out = (float*)d_out;

    const int N = in_sizes[0] / CCH;  // 4,000,000 points
    const int M = out_size / CCH;     // 500,000 segments

    // binned-path ws layout: counts[M] | offsets[M] | bsums[4096] | slots[N]
    const size_t need = (size_t)M * 4u * 2u + 4096u * 4u + (size_t)N * 4u;

    if (ws_size >= need) {
        char* base = (char*)d_ws;
        unsigned* counts  = (unsigned*)base;
        unsigned* offsets = (unsigned*)(base + (size_t)M * 4);
        unsigned* bsums   = (unsigned*)(base + (size_t)M * 8);
        unsigned* slots   = (unsigned*)(base + (size_t)M * 8 + 4096 * 4);

        const int nb = (M + 1023) / 1024;  // 489 blocks <= 1024

        zero_u32<<<(M + 255) / 256, 256, 0, stream>>>(counts, M);
        hist_kernel<<<(N + 255) / 256, 256, 0, stream>>>(seg, counts, N, M);

        scan1<<<nb, 1024, 0, stream>>>(counts, offsets, bsums, M);
        scan1<<<1, 1024, 0, stream>>>(bsums, bsums, nullptr, nb);
        scan_add<<<nb, 1024, 0, stream>>>(offsets, bsums, M);

        scatter_slots<<<(N + 255) / 256, 256, 0, stream>>>(seg, offsets, slots, N, M);

        long long total = (long long)M * CCH;  // 8M threads
        gather_mean<<<(int)((total + 255) / 256), 256, 0, stream>>>(
            in, slots, offsets, counts, out, M, N);
    } else {
        // fallback: direct atomics (known-good round-1 path)
        float* counts = (float*)d_ws;
        int n4 = out_size / 4;
        zero_f4<<<(n4 + 255) / 256, 256, 0, stream>>>((float4*)d_out, n4);
        zero_f<<<(M + 255) / 256, 256, 0, stream>>>(counts, M);
        long long total = (long long)N * CCH;
        scatter_add_kernel<<<(int)((total + 255) / 256), 256, 0, stream>>>(
            in, seg, out, counts, N);
        finalize_kernel<<<(n4 + 255) / 256, 256, 0, stream>>>(
            (float4*)d_out, counts, n4);
    }
}

// Round 4
// 668.466 us; speedup vs baseline: 1.5512x; 1.5512x over previous
//
#include <hip/hip_runtime.h>
#include <hip/hip_fp16.h>

#define CCH 16

// ======================= zero helpers =======================
__global__ void zero_f(float* __restrict__ p, int n) {
    int i = blockIdx.x * blockDim.x + threadIdx.x;
    if (i < n) p[i] = 0.0f;
}

__global__ void zero_f4(float4* __restrict__ p, int n4) {
    int i = blockIdx.x * blockDim.x + threadIdx.x;
    if (i < n4) p[i] = make_float4(0.f, 0.f, 0.f, 0.f);
}

// ======================= packed-f16 atomic path =======================
// One thread per (point, channel-pair): 8 threads/point. Lane cp reads
// float2 (8B) -> 64B contiguous per point, fully coalesced. Each thread
// issues ONE pk_add_f16 atomic (2 channels) -> 32M sum atomics + 4M count
// atomics vs R1's 64M + 4M.
__global__ void scatter_add_h2(const float2* __restrict__ in2,
                               const int* __restrict__ seg,
                               __half2* __restrict__ sums,
                               float* __restrict__ counts,
                               int N) {
    int tid = blockIdx.x * blockDim.x + threadIdx.x;   // 8*N threads
    int p = tid >> 3;
    int cp = tid & 7;
    if (p >= N) return;
    int s = seg[p];                  // 8 lanes broadcast one dword
    float2 v = in2[tid];
    __half2 h = __floats2half2_rn(v.x, v.y);
    // global_atomic_pk_add_f16 (HW, non-returning)
    unsafeAtomicAdd(&sums[(size_t)s * 8 + cp], h);
    if (cp == 0) unsafeAtomicAdd(&counts[s], 1.0f);
}

// finalize: out[s][2cp..2cp+1] = sums_h2 / max(count,1)
__global__ void finalize_h2(const __half2* __restrict__ sums,
                            const float* __restrict__ counts,
                            float2* __restrict__ out,
                            int total /* = M*8 */) {
    int i = blockIdx.x * blockDim.x + threadIdx.x;
    if (i >= total) return;
    int s = i >> 3;
    float inv = 1.0f / fmaxf(counts[s], 1.0f);
    float2 v = __half22float2(sums[i]);
    out[i] = make_float2(v.x * inv, v.y * inv);
}

// ======================= fallback (round-1 fp32 atomic) path =======================
__global__ void scatter_add_kernel(const float* __restrict__ in,
                                   const int* __restrict__ seg,
                                   float* __restrict__ sums,
                                   float* __restrict__ counts,
                                   int N) {
    int tid = blockIdx.x * blockDim.x + threadIdx.x;
    int p = tid >> 4;
    int c = tid & 15;
    if (p >= N) return;
    int s = seg[p];
    float v = in[tid];
    unsafeAtomicAdd(&sums[s * CCH + c], v);
    if (c == 0) unsafeAtomicAdd(&counts[s], 1.0f);
}

__global__ void finalize_kernel(float4* __restrict__ out,
                                const float* __restrict__ counts,
                                int n4) {
    int i = blockIdx.x * blockDim.x + threadIdx.x;
    if (i >= n4) return;
    int m = i >> 2;
    float inv = 1.0f / fmaxf(counts[m], 1.0f);
    float4 v = out[i];
    v.x *= inv; v.y *= inv; v.z *= inv; v.w *= inv;
    out[i] = v;
}

// ======================= launch =======================
extern "C" void kernel_launch(void* const* d_in, const int* in_sizes, int n_in,
                              void* d_out, int out_size, void* d_ws, size_t ws_size,
                              hipStream_t stream) {
    const float* in  = (const float*)d_in[0];
    const int*   seg = (const int*)d_in[1];
    float* out = (float*)d_out;

    const int N = in_sizes[0] / CCH;  // 4,000,000 points
    const int M = out_size / CCH;     // 500,000 segments

    // ws layout: sums_h2[M*8] (16 MB) | counts[M] (2 MB)
    const size_t need = (size_t)M * 8 * sizeof(__half2) + (size_t)M * sizeof(float);

    if (ws_size >= need) {
        __half2* sums = (__half2*)d_ws;
        float* counts = (float*)((char*)d_ws + (size_t)M * 8 * sizeof(__half2));

        // zero sums (16 MB) + counts (2 MB)
        {
            int n4 = (int)((size_t)M * 8 * sizeof(__half2) / sizeof(float4));
            zero_f4<<<(n4 + 255) / 256, 256, 0, stream>>>((float4*)sums, n4);
            zero_f<<<(M + 255) / 256, 256, 0, stream>>>(counts, M);
        }

        // scatter: 8 threads per point, pk_add_f16 atomics
        {
            long long total = (long long)N * 8;
            scatter_add_h2<<<(int)((total + 255) / 256), 256, 0, stream>>>(
                (const float2*)in, seg, sums, counts, N);
        }

        // finalize: convert + divide
        {
            int total = M * 8;
            finalize_h2<<<(total + 255) / 256, 256, 0, stream>>>(
                sums, counts, (float2*)out, total);
        }
    } else {
        // fallback: round-1 fp32 atomic path (needs only counts[M] in ws)
        float* counts = (float*)d_ws;
        int n4 = out_size / 4;
        zero_f4<<<(n4 + 255) / 256, 256, 0, stream>>>((float4*)d_out, n4);
        zero_f<<<(M + 255) / 256, 256, 0, stream>>>(counts, M);
        long long total = (long long)N * CCH;
        scatter_add_kernel<<<(int)((total + 255) / 256), 256, 0, stream>>>(
            in, seg, out, counts, N);
        finalize_kernel<<<(n4 + 255) / 256, 256, 0, stream>>>(
            (float4*)d_out, counts, n4);
    }
}